// Round 4
// baseline (379.093 us; speedup 1.0000x reference)
//
#include <hip/hip_runtime.h>

#define NEQ_   4096
#define XDIM_  6144
#define EEDGES 32768

typedef __bf16 bf16x8 __attribute__((ext_vector_type(8)));
typedef float  f32x4  __attribute__((ext_vector_type(4)));

__device__ __forceinline__ unsigned short f2bf(float f) {
    union { float f; unsigned u; } v; v.f = f;
    unsigned r = v.u + 0x7FFFu + ((v.u >> 16) & 1u);   // RNE
    return (unsigned short)(r >> 16);
}

// ---- GCN prologue (validated rounds 1-3) ----

__global__ void gcn_init(int* __restrict__ c1, float* __restrict__ S) {
    int i = blockIdx.x * 256 + threadIdx.x;
    if (i < NEQ_) { c1[i] = 0; S[i] = 0.f; }
}

__global__ void gcn_hist(const int* __restrict__ dst, int* __restrict__ c1) {
    int e = blockIdx.x * 256 + threadIdx.x;
    if (e < EEDGES) atomicAdd(&c1[dst[e]], 1);
}

__global__ void gcn_dinv(const int* __restrict__ c1, float* __restrict__ dinv) {
    int i = blockIdx.x * 256 + threadIdx.x;
    if (i < NEQ_) dinv[i] = rsqrtf(512.f * (float)c1[i] + 1.f);
}

__global__ void gcn_scatter(const int* __restrict__ src, const int* __restrict__ dst,
                            const float* __restrict__ x, const float* __restrict__ dinv,
                            float* __restrict__ S) {
    int e = blockIdx.x * 256 + threadIdx.x;
    if (e < EEDGES) {
        int s = src[e], d = dst[e];
        float xf = x[(size_t)(s & 511) * XDIM_ + (s >> 9)];
        atomicAdd(&S[d], dinv[s] * xf);
    }
}

__global__ void build_z(const float* __restrict__ x, const int* __restrict__ c1,
                        const float* __restrict__ dinv, const float* __restrict__ S,
                        const float* __restrict__ gw, const float* __restrict__ gb,
                        unsigned short* __restrict__ z) {
    int i = blockIdx.x * 256 + threadIdx.x;  // 0..6143
    int b = blockIdx.y;                      // 0..511
    float xv = x[(size_t)b * XDIM_ + i];
    float v;
    if (i >= NEQ_) {
        v = xv;
    } else {
        float w00 = gw[0], b0 = gb[0];
        if (i >= 8) {
            v = fmaxf(w00 * xv + b0, 0.f);
        } else {
            int n = i * 512 + b;
            float deg = 512.f * (float)c1[n] + 1.f;
            float outv = w00 * (512.f * dinv[n] * S[n] + xv / deg);
            v = fmaxf(outv + b0, 0.f);
        }
    }
    z[(size_t)b * XDIM_ + i] = f2bf(v);
}

// ---- weight transpose+convert: W[K][N] f32 -> Wt[N][K] bf16 (validated r3) ----
__global__ __launch_bounds__(256)
void tcvt(const float* __restrict__ W, unsigned short* __restrict__ Wt, int K, int N) {
    int lane = threadIdx.x & 63, wave = threadIdx.x >> 6;
    int n  = blockIdx.x * 16 + (lane >> 2);
    int kb = (blockIdx.y * 4 + wave) * 32 + (lane & 3) * 8;
    union { unsigned short h[8]; uint4 u; } cv;
    #pragma unroll
    for (int j = 0; j < 8; ++j) cv.h[j] = f2bf(W[(size_t)(kb + j) * N + n]);
    *(uint4*)(Wt + (size_t)n * K + kb) = cv.u;
}

// ---- register-direct MFMA GEMM: no LDS, no barriers ----
// One wave = one 32x32 output tile (2x2 of 16x16x32), BK=64, 1-iter prefetch.
// Fragments loaded straight from global (16 B/lane contiguous); latency hidden
// by 16 waves/CU + prefetch; weights are LLC/L2-resident.
__global__ __launch_bounds__(256, 4)
void gemm_reg(const unsigned short* __restrict__ A,   // [M][K] bf16
              const unsigned short* __restrict__ Bt,  // [N][K] bf16
              float* __restrict__ P,                  // [S][M][N] f32
              int M, int N, int K, int kChunk, int tilesM, int tilesN)
{
    const int lane = threadIdx.x & 63;
    const int wid  = (blockIdx.x * 256 + threadIdx.x) >> 6;
    const int tiles = tilesM * tilesN;
    const int si  = wid / tiles;
    const int rem = wid - si * tiles;
    const int mi  = rem % tilesM;         // fast: 16 M-waves share one B panel
    const int ni  = rem / tilesM;
    const int m0 = mi * 32, n0 = ni * 32;
    const int fr = lane & 15, fko = (lane >> 4) * 8;
    const int k0 = si * kChunk;

    const unsigned short* pa0 = A  + (size_t)(m0 + fr) * K + k0 + fko;
    const unsigned short* pa1 = pa0 + (size_t)16 * K;
    const unsigned short* pb0 = Bt + (size_t)(n0 + fr) * K + k0 + fko;
    const unsigned short* pb1 = pb0 + (size_t)16 * K;

    f32x4 acc[2][2] = {};

    bf16x8 cA[2][2], cB[2][2];   // [kh][tile]
    cA[0][0] = *(const bf16x8*)(pa0);      cA[0][1] = *(const bf16x8*)(pa1);
    cA[1][0] = *(const bf16x8*)(pa0 + 32); cA[1][1] = *(const bf16x8*)(pa1 + 32);
    cB[0][0] = *(const bf16x8*)(pb0);      cB[0][1] = *(const bf16x8*)(pb1);
    cB[1][0] = *(const bf16x8*)(pb0 + 32); cB[1][1] = *(const bf16x8*)(pb1 + 32);

    const int iters = kChunk >> 6;
    #pragma unroll 2
    for (int it = 0; it < iters - 1; ++it) {
        const int o = (it + 1) << 6;
        bf16x8 nA[2][2], nB[2][2];
        nA[0][0] = *(const bf16x8*)(pa0 + o);      nA[0][1] = *(const bf16x8*)(pa1 + o);
        nA[1][0] = *(const bf16x8*)(pa0 + o + 32); nA[1][1] = *(const bf16x8*)(pa1 + o + 32);
        nB[0][0] = *(const bf16x8*)(pb0 + o);      nB[0][1] = *(const bf16x8*)(pb1 + o);
        nB[1][0] = *(const bf16x8*)(pb0 + o + 32); nB[1][1] = *(const bf16x8*)(pb1 + o + 32);

        #pragma unroll
        for (int kh = 0; kh < 2; ++kh)
            #pragma unroll
            for (int mt = 0; mt < 2; ++mt)
                #pragma unroll
                for (int nt = 0; nt < 2; ++nt)
                    acc[mt][nt] = __builtin_amdgcn_mfma_f32_16x16x32_bf16(
                        cA[kh][mt], cB[kh][nt], acc[mt][nt], 0, 0, 0);

        #pragma unroll
        for (int kh = 0; kh < 2; ++kh)
            #pragma unroll
            for (int t = 0; t < 2; ++t) { cA[kh][t] = nA[kh][t]; cB[kh][t] = nB[kh][t]; }
    }
    #pragma unroll
    for (int kh = 0; kh < 2; ++kh)
        #pragma unroll
        for (int mt = 0; mt < 2; ++mt)
            #pragma unroll
            for (int nt = 0; nt < 2; ++nt)
                acc[mt][nt] = __builtin_amdgcn_mfma_f32_16x16x32_bf16(
                    cA[kh][mt], cB[kh][nt], acc[mt][nt], 0, 0, 0);

    float* Pp = P + (size_t)si * M * N;
    const int col = lane & 15, qr = (lane >> 4) * 4;
    #pragma unroll
    for (int mt = 0; mt < 2; ++mt)
    #pragma unroll
    for (int nt = 0; nt < 2; ++nt) {
        int gm = m0 + mt * 16 + qr;
        int gn = n0 + nt * 16 + col;
        #pragma unroll
        for (int r = 0; r < 4; ++r)
            Pp[(size_t)(gm + r) * N + gn] = acc[mt][nt][r];
    }
}

// ---- split-K reduce + bias (+relu) epilogue ----
template<bool RELU, bool OUTBF16>
__global__ __launch_bounds__(256)
void reduce_ep(const float* __restrict__ P, const float* __restrict__ bias,
               void* __restrict__ Out, int MN, int N, int S)
{
    int e = (blockIdx.x * 256 + threadIdx.x) * 4;
    if (e >= MN) return;
    f32x4 v = *(const f32x4*)(P + e);
    for (int s = 1; s < S; ++s) v += *(const f32x4*)(P + (size_t)s * MN + e);
    int nb = e % N;
    f32x4 bv = *(const f32x4*)(bias + nb);
    v += bv;
    if (RELU) {
        #pragma unroll
        for (int j = 0; j < 4; ++j) v[j] = fmaxf(v[j], 0.f);
    }
    if (OUTBF16) {
        union { unsigned short h[4]; uint2 u; } cv;
        #pragma unroll
        for (int j = 0; j < 4; ++j) cv.h[j] = f2bf(v[j]);
        *(uint2*)((unsigned short*)Out + e) = cv.u;
    } else {
        *(f32x4*)((float*)Out + e) = v;
    }
}

extern "C" void kernel_launch(void* const* d_in, const int* in_sizes, int n_in,
                              void* d_out, int out_size, void* d_ws, size_t ws_size,
                              hipStream_t stream)
{
    const float* x  = (const float*)d_in[0];
    const int*   ei = (const int*)d_in[1];
    const float* gw = (const float*)d_in[2];
    const float* gb = (const float*)d_in[3];
    const float* W1 = (const float*)d_in[4];
    const float* b1 = (const float*)d_in[5];
    const float* W2 = (const float*)d_in[6];
    const float* b2 = (const float*)d_in[7];
    const float* W3 = (const float*)d_in[8];
    const float* b3 = (const float*)d_in[9];
    float* out = (float*)d_out;

    char* ws = (char*)d_ws;
    unsigned short* z   = (unsigned short*)(ws);               // 6,291,456 B
    unsigned short* z1  = (unsigned short*)(ws + 6291456);     // 2,097,152 B
    unsigned short* z2  = (unsigned short*)(ws + 8388608);     // 2,097,152 B
    unsigned short* W1t = (unsigned short*)(ws + 10485760);    // 25,165,824 B
    unsigned short* W2t = (unsigned short*)(ws + 35651584);    // 8,388,608 B
    unsigned short* W3t = (unsigned short*)(ws + 44040192);    // 16,777,216 B
    float* P            = (float*)        (ws + 60817408);     // 33,554,432 B
    int*   c1           = (int*)          (ws + 94371840);
    float* Sg           = (float*)        (ws + 94388224);
    float* dinv         = (float*)        (ws + 94404608);

    // weight transpose+convert (f32 [K][N] -> bf16 [N][K])
    hipLaunchKernelGGL(tcvt, dim3(128, 48), dim3(256), 0, stream, W1, W1t, 6144, 2048);
    hipLaunchKernelGGL(tcvt, dim3(128, 16), dim3(256), 0, stream, W2, W2t, 2048, 2048);
    hipLaunchKernelGGL(tcvt, dim3(256, 16), dim3(256), 0, stream, W3, W3t, 2048, 4096);

    // GCN + z assembly
    hipLaunchKernelGGL(gcn_init,    dim3(16),      dim3(256), 0, stream, c1, Sg);
    hipLaunchKernelGGL(gcn_hist,    dim3(128),     dim3(256), 0, stream, ei + EEDGES, c1);
    hipLaunchKernelGGL(gcn_dinv,    dim3(16),      dim3(256), 0, stream, c1, dinv);
    hipLaunchKernelGGL(gcn_scatter, dim3(128),     dim3(256), 0, stream, ei, ei + EEDGES, x, dinv, Sg);
    hipLaunchKernelGGL(build_z,     dim3(24, 512), dim3(256), 0, stream, x, c1, dinv, Sg, gw, gb, z);

    // L1: z[512,6144] @ W1 -> z1 (relu, bf16). tiles 16x64, S=4 (chunk 1536, 24 iters), 4096 waves
    hipLaunchKernelGGL(gemm_reg, dim3(1024), dim3(256), 0, stream, z,  W1t, P, 512, 2048, 6144, 1536, 16, 64);
    hipLaunchKernelGGL((reduce_ep<true, true>),  dim3(1024), dim3(256), 0, stream, P, b1, (void*)z1, 512 * 2048, 2048, 4);

    // L2: z1[512,2048] @ W2 -> z2 (relu, bf16). tiles 16x64, S=4 (chunk 512, 8 iters)
    hipLaunchKernelGGL(gemm_reg, dim3(1024), dim3(256), 0, stream, z1, W2t, P, 512, 2048, 2048, 512, 16, 64);
    hipLaunchKernelGGL((reduce_ep<true, true>),  dim3(1024), dim3(256), 0, stream, P, b2, (void*)z2, 512 * 2048, 2048, 4);

    // L3: z2[512,2048] @ W3 -> out (f32). tiles 16x128, S=2 (chunk 1024, 16 iters)
    hipLaunchKernelGGL(gemm_reg, dim3(1024), dim3(256), 0, stream, z2, W3t, P, 512, 4096, 2048, 1024, 16, 128);
    hipLaunchKernelGGL((reduce_ep<false, false>), dim3(2048), dim3(256), 0, stream, P, b3, (void*)out, 512 * 4096, 4096, 2);
}

// Round 5
// 275.304 us; speedup vs baseline: 1.3770x; 1.3770x over previous
//
#include <hip/hip_runtime.h>

#define NEQ_   4096
#define XDIM_  6144
#define EEDGES 32768

typedef __bf16 bf16x8 __attribute__((ext_vector_type(8)));
typedef float  f32x4  __attribute__((ext_vector_type(4)));

__device__ __forceinline__ unsigned short f2bf(float f) {
    union { float f; unsigned u; } v; v.f = f;
    unsigned r = v.u + 0x7FFFu + ((v.u >> 16) & 1u);   // RNE
    return (unsigned short)(r >> 16);
}
__device__ __forceinline__ float bf2f(unsigned short h) {
    union { unsigned u; float f; } v; v.u = ((unsigned)h) << 16; return v.f;
}

__device__ __forceinline__ void gll16(const void* g, void* l) {
    __builtin_amdgcn_global_load_lds(
        (const __attribute__((address_space(1))) unsigned int*)g,
        (__attribute__((address_space(3))) unsigned int*)l, 16, 0, 0);
}

// ---- GCN prologue (validated rounds 1-4) ----

__global__ void gcn_init(int* __restrict__ c1, float* __restrict__ S) {
    int i = blockIdx.x * 256 + threadIdx.x;
    if (i < NEQ_) { c1[i] = 0; S[i] = 0.f; }
}

__global__ void gcn_hist(const int* __restrict__ dst, int* __restrict__ c1) {
    int e = blockIdx.x * 256 + threadIdx.x;
    if (e < EEDGES) atomicAdd(&c1[dst[e]], 1);
}

__global__ void gcn_dinv(const int* __restrict__ c1, float* __restrict__ dinv) {
    int i = blockIdx.x * 256 + threadIdx.x;
    if (i < NEQ_) dinv[i] = rsqrtf(512.f * (float)c1[i] + 1.f);
}

__global__ void gcn_scatter(const int* __restrict__ src, const int* __restrict__ dst,
                            const float* __restrict__ x, const float* __restrict__ dinv,
                            float* __restrict__ S) {
    int e = blockIdx.x * 256 + threadIdx.x;
    if (e < EEDGES) {
        int s = src[e], d = dst[e];
        float xf = x[(size_t)(s & 511) * XDIM_ + (s >> 9)];
        atomicAdd(&S[d], dinv[s] * xf);
    }
}

__global__ void build_z(const float* __restrict__ x, const int* __restrict__ c1,
                        const float* __restrict__ dinv, const float* __restrict__ S,
                        const float* __restrict__ gw, const float* __restrict__ gb,
                        unsigned short* __restrict__ z) {
    int i = blockIdx.x * 256 + threadIdx.x;  // 0..6143
    int b = blockIdx.y;                      // 0..511
    float xv = x[(size_t)b * XDIM_ + i];
    float v;
    if (i >= NEQ_) {
        v = xv;
    } else {
        float w00 = gw[0], b0 = gb[0];
        if (i >= 8) {
            v = fmaxf(w00 * xv + b0, 0.f);
        } else {
            int n = i * 512 + b;
            float deg = 512.f * (float)c1[n] + 1.f;
            float outv = w00 * (512.f * dinv[n] * S[n] + xv / deg);
            v = fmaxf(outv + b0, 0.f);
        }
    }
    z[(size_t)b * XDIM_ + i] = f2bf(v);
}

// ---- weight transpose+convert: W[K][N] f32 -> Wt[N][K] bf16 (validated r3) ----
__global__ __launch_bounds__(256)
void tcvt(const float* __restrict__ W, unsigned short* __restrict__ Wt, int K, int N) {
    int lane = threadIdx.x & 63, wave = threadIdx.x >> 6;
    int n  = blockIdx.x * 16 + (lane >> 2);
    int kb = (blockIdx.y * 4 + wave) * 32 + (lane & 3) * 8;
    union { unsigned short h[8]; uint4 u; } cv;
    #pragma unroll
    for (int j = 0; j < 8; ++j) cv.h[j] = f2bf(W[(size_t)(kb + j) * N + n]);
    *(uint4*)(Wt + (size_t)n * K + kb) = cv.u;
}

// ---- 64(M)x128(N)-tile MFMA GEMM, BK=64, 4 waves (each 32x64 = 2x4 MFMA) ----
// LDS panels [kh][row][32] (A) / [rh*2+kh][row][32] (B); gll16 dst byte addr
// = inst_base + tid*16 exactly (wave-uniform-base honored).
// Split-K partials stored as bf16 to P[S][M][N].
__global__ __launch_bounds__(256, 4)
void gemm64x128(const unsigned short* __restrict__ A,   // [M][K] bf16
                const unsigned short* __restrict__ Bt,  // [N][K] bf16
                unsigned short* __restrict__ P,         // [S][M][N] bf16
                int M, int N, int K, int kChunk)
{
    __shared__ unsigned short As[2 * 64 * 32];   // 8 KB  [kh][row][32]
    __shared__ unsigned short Bs[4 * 64 * 32];   // 16 KB [rh*2+kh][row][32]
    const int tid = threadIdx.x, lane = tid & 63, wave = tid >> 6;
    const int m0 = blockIdx.x * 64, n0 = blockIdx.y * 128;
    const int wm = (wave >> 1) * 32;          // 0 or 32
    const int wn = (wave & 1) * 64;           // 0 or 64
    const int fr = lane & 15, fko = (lane >> 4) * 8;
    const int k0 = blockIdx.z * kChunk, k1 = k0 + kChunk;

    // staging: thread t -> row t>>2, k-off (t&3)*8 within a [64 x 32] panel
    const int srow = tid >> 2;
    const int sko  = (tid & 3) * 8;
    const size_t aoff  = (size_t)(m0 + srow) * K + sko;
    const size_t boff0 = (size_t)(n0 + srow) * K + sko;
    const size_t boff1 = (size_t)(n0 + 64 + srow) * K + sko;
    unsigned short* asl0 = &As[srow * 32 + sko];
    unsigned short* asl1 = &As[2048 + srow * 32 + sko];
    unsigned short* bsl00 = &Bs[srow * 32 + sko];            // rh=0 kh=0
    unsigned short* bsl01 = &Bs[2048 + srow * 32 + sko];     // rh=0 kh=1
    unsigned short* bsl10 = &Bs[4096 + srow * 32 + sko];     // rh=1 kh=0
    unsigned short* bsl11 = &Bs[6144 + srow * 32 + sko];     // rh=1 kh=1

    const int bbase = (wave & 1) * 4096;     // rh is wave-uniform

    f32x4 acc[2][4] = {};

    for (int kk = k0; kk < k1; kk += 64) {
        gll16(A + aoff + kk,       asl0);
        gll16(A + aoff + kk + 32,  asl1);
        gll16(Bt + boff0 + kk,      bsl00);
        gll16(Bt + boff0 + kk + 32, bsl01);
        gll16(Bt + boff1 + kk,      bsl10);
        gll16(Bt + boff1 + kk + 32, bsl11);
        __syncthreads();

        bf16x8 af[2][2], bf[4][2];   // [tile][kh]
        #pragma unroll
        for (int kh = 0; kh < 2; ++kh) {
            #pragma unroll
            for (int mt = 0; mt < 2; ++mt)
                af[mt][kh] = *(const bf16x8*)(&As[kh * 2048 + (wm + mt * 16 + fr) * 32 + fko]);
            #pragma unroll
            for (int nt = 0; nt < 4; ++nt)
                bf[nt][kh] = *(const bf16x8*)(&Bs[bbase + kh * 2048 + (nt * 16 + fr) * 32 + fko]);
        }
        #pragma unroll
        for (int kh = 0; kh < 2; ++kh)
            #pragma unroll
            for (int mt = 0; mt < 2; ++mt)
                #pragma unroll
                for (int nt = 0; nt < 4; ++nt)
                    acc[mt][nt] = __builtin_amdgcn_mfma_f32_16x16x32_bf16(
                        af[mt][kh], bf[nt][kh], acc[mt][nt], 0, 0, 0);

        __syncthreads();
    }

    unsigned short* Pp = P + (size_t)blockIdx.z * M * N;
    const int col = lane & 15, qr = (lane >> 4) * 4;
    #pragma unroll
    for (int mt = 0; mt < 2; ++mt)
    #pragma unroll
    for (int nt = 0; nt < 4; ++nt) {
        int gm = m0 + wm + mt * 16 + qr;
        int gn = n0 + wn + nt * 16 + col;
        #pragma unroll
        for (int r = 0; r < 4; ++r)
            Pp[(size_t)(gm + r) * N + gn] = f2bf(acc[mt][nt][r]);
    }
}

// ---- split-K reduce + bias (+relu) epilogue; P is bf16, N must be pow2 ----
template<bool RELU, bool OUTBF16>
__global__ __launch_bounds__(256)
void reduce_ep(const unsigned short* __restrict__ P, const float* __restrict__ bias,
               void* __restrict__ Out, int MN, int N, int S)
{
    int e = (blockIdx.x * 256 + threadIdx.x) * 4;
    if (e >= MN) return;
    float v0 = 0.f, v1 = 0.f, v2 = 0.f, v3 = 0.f;
    for (int s = 0; s < S; ++s) {
        union { uint2 u; unsigned short h[4]; } p;
        p.u = *(const uint2*)(P + (size_t)s * MN + e);
        v0 += bf2f(p.h[0]); v1 += bf2f(p.h[1]); v2 += bf2f(p.h[2]); v3 += bf2f(p.h[3]);
    }
    int nb = e & (N - 1);
    f32x4 bv = *(const f32x4*)(bias + nb);
    v0 += bv[0]; v1 += bv[1]; v2 += bv[2]; v3 += bv[3];
    if (RELU) {
        v0 = fmaxf(v0, 0.f); v1 = fmaxf(v1, 0.f);
        v2 = fmaxf(v2, 0.f); v3 = fmaxf(v3, 0.f);
    }
    if (OUTBF16) {
        union { unsigned short h[4]; uint2 u; } cv;
        cv.h[0] = f2bf(v0); cv.h[1] = f2bf(v1); cv.h[2] = f2bf(v2); cv.h[3] = f2bf(v3);
        *(uint2*)((unsigned short*)Out + e) = cv.u;
    } else {
        f32x4 v = { v0, v1, v2, v3 };
        *(f32x4*)((float*)Out + e) = v;
    }
}

extern "C" void kernel_launch(void* const* d_in, const int* in_sizes, int n_in,
                              void* d_out, int out_size, void* d_ws, size_t ws_size,
                              hipStream_t stream)
{
    const float* x  = (const float*)d_in[0];
    const int*   ei = (const int*)d_in[1];
    const float* gw = (const float*)d_in[2];
    const float* gb = (const float*)d_in[3];
    const float* W1 = (const float*)d_in[4];
    const float* b1 = (const float*)d_in[5];
    const float* W2 = (const float*)d_in[6];
    const float* b2 = (const float*)d_in[7];
    const float* W3 = (const float*)d_in[8];
    const float* b3 = (const float*)d_in[9];
    float* out = (float*)d_out;

    char* ws = (char*)d_ws;
    unsigned short* z   = (unsigned short*)(ws);               // 6,291,456 B
    unsigned short* z1  = (unsigned short*)(ws + 6291456);     // 2,097,152 B
    unsigned short* z2  = (unsigned short*)(ws + 8388608);     // 2,097,152 B
    unsigned short* W1t = (unsigned short*)(ws + 10485760);    // 25,165,824 B
    unsigned short* W2t = (unsigned short*)(ws + 35651584);    // 8,388,608 B
    unsigned short* W3t = (unsigned short*)(ws + 44040192);    // 16,777,216 B
    unsigned short* P   = (unsigned short*)(ws + 60817408);    // bf16 partials, max 16.8 MB
    int*   c1           = (int*)          (ws + 94371840);
    float* Sg           = (float*)        (ws + 94388224);
    float* dinv         = (float*)        (ws + 94404608);

    // weight transpose+convert (f32 [K][N] -> bf16 [N][K])
    hipLaunchKernelGGL(tcvt, dim3(128, 48), dim3(256), 0, stream, W1, W1t, 6144, 2048);
    hipLaunchKernelGGL(tcvt, dim3(128, 16), dim3(256), 0, stream, W2, W2t, 2048, 2048);
    hipLaunchKernelGGL(tcvt, dim3(256, 16), dim3(256), 0, stream, W3, W3t, 2048, 4096);

    // GCN + z assembly
    hipLaunchKernelGGL(gcn_init,    dim3(16),      dim3(256), 0, stream, c1, Sg);
    hipLaunchKernelGGL(gcn_hist,    dim3(128),     dim3(256), 0, stream, ei + EEDGES, c1);
    hipLaunchKernelGGL(gcn_dinv,    dim3(16),      dim3(256), 0, stream, c1, dinv);
    hipLaunchKernelGGL(gcn_scatter, dim3(128),     dim3(256), 0, stream, ei, ei + EEDGES, x, dinv, Sg);
    hipLaunchKernelGGL(build_z,     dim3(24, 512), dim3(256), 0, stream, x, c1, dinv, Sg, gw, gb, z);

    // L1: z[512,6144] @ W1 -> z1 (relu, bf16). tiles 8x16, S=8 (chunk 768, 12 iters), 1024 blocks
    hipLaunchKernelGGL(gemm64x128, dim3(8, 16, 8), dim3(256), 0, stream, z,  W1t, P, 512, 2048, 6144, 768);
    hipLaunchKernelGGL((reduce_ep<true, true>),  dim3(1024), dim3(256), 0, stream, P, b1, (void*)z1, 512 * 2048, 2048, 8);

    // L2: z1[512,2048] @ W2 -> z2 (relu, bf16). tiles 8x16, S=8 (chunk 256, 4 iters), 1024 blocks
    hipLaunchKernelGGL(gemm64x128, dim3(8, 16, 8), dim3(256), 0, stream, z1, W2t, P, 512, 2048, 2048, 256);
    hipLaunchKernelGGL((reduce_ep<true, true>),  dim3(1024), dim3(256), 0, stream, P, b2, (void*)z2, 512 * 2048, 2048, 8);

    // L3: z2[512,2048] @ W3 -> out (f32). tiles 8x32, S=4 (chunk 512, 8 iters), 1024 blocks
    hipLaunchKernelGGL(gemm64x128, dim3(8, 32, 4), dim3(256), 0, stream, z2, W3t, P, 512, 4096, 2048, 512);
    hipLaunchKernelGGL((reduce_ep<false, false>), dim3(2048), dim3(256), 0, stream, P, b3, (void*)out, 512 * 4096, 4096, 4);
}